// Round 6
// baseline (1002.600 us; speedup 1.0000x reference)
//
#include <hip/hip_runtime.h>
#include <math.h>

#define NN 50000
#define NE 600000
#define DIM 128
#define NL 12

typedef short bf16x8 __attribute__((ext_vector_type(8)));
typedef float f32x4 __attribute__((ext_vector_type(4)));

__device__ __forceinline__ uint f2b_rne(float f) {
    uint u = __float_as_uint(f);
    return (u + 0x7fffu + ((u >> 16) & 1u)) >> 16;
}

// ---------------- fused fp32 -> bf16 convert for all 4 tensors ----------------
#define NX8 (NN * DIM / 8)               // 800000
#define NW8 (NL * DIM * DIM / 8)         // 24576
#define NW18 (DIM * DIM / 8)             // 2048
__global__ void cvt_all(const float* __restrict__ x, const float* __restrict__ Wl,
                        const float* __restrict__ Wr, const float* __restrict__ W1,
                        ushort* __restrict__ xb, ushort* __restrict__ Wlb,
                        ushort* __restrict__ Wrb, ushort* __restrict__ W1b) {
    int i = blockIdx.x * blockDim.x + threadIdx.x;
    const float* in; ushort* out; int off;
    if (i < NX8)                        { in = x;  out = xb;  off = i; }
    else if (i < NX8 + NW8)             { in = Wl; out = Wlb; off = i - NX8; }
    else if (i < NX8 + 2 * NW8)         { in = Wr; out = Wrb; off = i - NX8 - NW8; }
    else if (i < NX8 + 2 * NW8 + NW18)  { in = W1; out = W1b; off = i - NX8 - 2 * NW8; }
    else return;
    const float4* p = reinterpret_cast<const float4*>(in);
    float4 v0 = p[off * 2], v1 = p[off * 2 + 1];
    uint4 o;
    o.x = (f2b_rne(v0.y) << 16) | f2b_rne(v0.x);
    o.y = (f2b_rne(v0.w) << 16) | f2b_rne(v0.z);
    o.z = (f2b_rne(v1.y) << 16) | f2b_rne(v1.x);
    o.w = (f2b_rne(v1.w) << 16) | f2b_rne(v1.z);
    reinterpret_cast<uint4*>(out)[off] = o;
}

// ---------------- CSR build ----------------
__global__ void count_kernel(const int* __restrict__ dst, int* __restrict__ counts) {
    int e = blockIdx.x * blockDim.x + threadIdx.x;
    if (e < NE) atomicAdd(&counts[dst[e]], 1);
}

__global__ __launch_bounds__(1024) void scan1_kernel(const int* __restrict__ counts,
                                                     int* __restrict__ offsets,
                                                     int* __restrict__ bsums) {
    int b = blockIdx.x, t = threadIdx.x;
    int i = b * 1024 + t;
    int lane = t & 63, wid = t >> 6;
    int val = (i < NN) ? counts[i] : 0;
#pragma unroll
    for (int o = 1; o < 64; o <<= 1) {
        int n = __shfl_up(val, o);
        if (lane >= o) val += n;
    }
    __shared__ int ws[16];
    if (lane == 63) ws[wid] = val;
    __syncthreads();
    if (wid == 0 && lane < 16) {
        int s = ws[lane];
#pragma unroll
        for (int o = 1; o < 16; o <<= 1) {
            int n = __shfl_up(s, o);
            if (lane >= o) s += n;
        }
        ws[lane] = s;
    }
    __syncthreads();
    if (wid) val += ws[wid - 1];
    if (i < NN) offsets[i + 1] = val;
    if (t == 1023) bsums[b] = val;
}

__global__ void scan2_kernel(const int* __restrict__ bsums, int* __restrict__ bbase, int nb) {
    int lane = threadIdx.x;
    int v = (lane < nb) ? bsums[lane] : 0;
    int val = v;
#pragma unroll
    for (int o = 1; o < 64; o <<= 1) {
        int n = __shfl_up(val, o);
        if (lane >= o) val += n;
    }
    if (lane < nb) bbase[lane] = val - v;   // exclusive
}

__global__ void scan3_kernel(int* __restrict__ offsets, const int* __restrict__ bbase) {
    int i = blockIdx.x * blockDim.x + threadIdx.x;
    if (i == 0) { offsets[0] = 0; return; }
    if (i <= NN) offsets[i] += bbase[(i - 1) >> 10];
}

__global__ void fill_kernel(const int* __restrict__ src, const int* __restrict__ dst,
                            const int* __restrict__ offsets, int* __restrict__ cursor,
                            int* __restrict__ csr) {
    int e = blockIdx.x * blockDim.x + threadIdx.x;
    if (e < NE) {
        int d = dst[e];
        int p = atomicAdd(&cursor[d], 1);
        csr[offsets[d] + p] = src[e];
    }
}

// ---------------- aggregation: one wave per node, full 256B row per gather ----------------
// 64 lanes x uint (2 bf16) = one row per load; unroll 16 -> up to 16 gathers in flight.
// Wave-uniform predication branch-skips masked slots (no wasted requests).
// AGGR: 0=sum, 1=mean, 2=max
template <int AGGR>
__global__ __launch_bounds__(256) void aggregate_kernel(
    const ushort* __restrict__ h, ushort* __restrict__ agg,
    const int* __restrict__ csr, const int* __restrict__ offsets) {
    int wid = (blockIdx.x * blockDim.x + threadIdx.x) >> 6;
    int l = threadIdx.x & 63;
    if (wid >= NN) return;
    int s0 = offsets[wid], s1 = offsets[wid + 1];
    const uint* hp = reinterpret_cast<const uint*>(h);   // row = 64 uints
    float ax, ay;
    if (AGGR == 2) { ax = ay = -INFINITY; } else { ax = ay = 0.f; }
    for (int e = s0; e < s1; e += 16) {
        uint u[16];
#pragma unroll
        for (int q = 0; q < 16; ++q) {
            if (e + q < s1)                       // wave-uniform: cheap scalar branch
                u[q] = hp[(size_t)csr[e + q] * 64 + l];
        }
#pragma unroll
        for (int q = 0; q < 16; ++q) {
            if (e + q < s1) {
                float fx = __uint_as_float(u[q] << 16);
                float fy = __uint_as_float(u[q] & 0xffff0000u);
                if (AGGR == 2) { ax = fmaxf(ax, fx); ay = fmaxf(ay, fy); }
                else           { ax += fx;           ay += fy; }
            }
        }
    }
    int deg = s1 - s0;
    if (AGGR == 1) {
        float inv = 1.f / (float)(deg > 0 ? deg : 1);
        ax *= inv; ay *= inv;
    }
    if (AGGR == 2 && deg == 0) { ax = ay = 0.f; }
    uint o = (f2b_rne(ay) << 16) | f2b_rne(ax);
    reinterpret_cast<uint*>(agg)[(size_t)wid * 64 + l] = o;
}

// ---------------- MFMA GEMM, no LDS, swapped operands ----------------
// C[n][:] = relu(A1[n] @ Wa^T [+ A2[n] @ Wb^T] + bias)
// Block = 4 waves x 32 rows = 128 rows; wave w owns rows blockIdx.x*128 + w*32 + (0..31)
// as 2 row-frags of 16. mfma(W-frag as A, node-frag as B) -> D[m=outcol][n=node]:
//   A-frag: lane holds W[c*16 + (l&15)][(l>>4)*8 ..+7]
//   B-frag: lane holds A[row0 + rf*16 + (l&15)][(l>>4)*8 ..+7]
//   D:      node col = l&15, out-col row = (l>>4)*4 + reg  -> packed uint2 stores
// In-place C==A1 is safe: each wave reads only its own 32 rows, stores last
// (acc data-dependency orders all loads before stores).
template <int NPASS>
__global__ __launch_bounds__(256) void gemm_kernel(
    const ushort* __restrict__ A1, const ushort* __restrict__ Wa,
    const ushort* __restrict__ A2, const ushort* __restrict__ Wb,
    const float* __restrict__ bias, ushort* __restrict__ C) {
    int t = threadIdx.x, w = t >> 6, l = t & 63;
    int lr = l & 15, lg = l >> 4;
    int row0 = blockIdx.x * 128 + w * 32;
    f32x4 acc[2][8];
#pragma unroll
    for (int rf = 0; rf < 2; ++rf)
#pragma unroll
        for (int c = 0; c < 8; ++c) acc[rf][c] = (f32x4){0.f, 0.f, 0.f, 0.f};
    int grow0 = min(row0 + lr, NN - 1);        // clamp; OOB discarded at store
    int grow1 = min(row0 + 16 + lr, NN - 1);

#pragma unroll
    for (int pass = 0; pass < NPASS; ++pass) {
        const ushort* A = pass ? A2 : A1;
        const ushort* W = pass ? Wb : Wa;
#pragma unroll
        for (int kk = 0; kk < 4; ++kk) {
            int ko = kk * 32 + lg * 8;
            bf16x8 nf0 = *reinterpret_cast<const bf16x8*>(A + (size_t)grow0 * DIM + ko);
            bf16x8 nf1 = *reinterpret_cast<const bf16x8*>(A + (size_t)grow1 * DIM + ko);
#pragma unroll
            for (int c = 0; c < 8; ++c) {
                bf16x8 wf = *reinterpret_cast<const bf16x8*>(
                    W + (size_t)(c * 16 + lr) * DIM + ko);
                acc[0][c] = __builtin_amdgcn_mfma_f32_16x16x32_bf16(wf, nf0, acc[0][c], 0, 0, 0);
                acc[1][c] = __builtin_amdgcn_mfma_f32_16x16x32_bf16(wf, nf1, acc[1][c], 0, 0, 0);
            }
        }
    }
#pragma unroll
    for (int rf = 0; rf < 2; ++rf) {
        int orow = row0 + rf * 16 + lr;
        if (orow < NN) {
#pragma unroll
            for (int c = 0; c < 8; ++c) {
                int col0 = c * 16 + lg * 4;
                float4 b4 = *reinterpret_cast<const float4*>(bias + col0);
                float v0 = fmaxf(acc[rf][c][0] + b4.x, 0.f);
                float v1 = fmaxf(acc[rf][c][1] + b4.y, 0.f);
                float v2 = fmaxf(acc[rf][c][2] + b4.z, 0.f);
                float v3 = fmaxf(acc[rf][c][3] + b4.w, 0.f);
                uint2 o;
                o.x = (f2b_rne(v1) << 16) | f2b_rne(v0);
                o.y = (f2b_rne(v3) << 16) | f2b_rne(v2);
                *reinterpret_cast<uint2*>(C + (size_t)orow * DIM + col0) = o;
            }
        }
    }
}

// ---------------- final 128 -> 2 projection ----------------
__global__ void out_kernel(const ushort* __restrict__ h2, const float* __restrict__ W2,
                           const float* __restrict__ b2, float* __restrict__ out) {
    int wid = (blockIdx.x * blockDim.x + threadIdx.x) >> 6;
    int lane = threadIdx.x & 63;
    if (wid >= NN) return;
    uint u = reinterpret_cast<const uint*>(h2)[(size_t)wid * 64 + lane];
    float vx = __uint_as_float(u << 16), vy = __uint_as_float(u & 0xffff0000u);
    float2 w0 = *reinterpret_cast<const float2*>(W2 + lane * 2);
    float2 w1 = *reinterpret_cast<const float2*>(W2 + DIM + lane * 2);
    float s0 = vx * w0.x + vy * w0.y;
    float s1 = vx * w1.x + vy * w1.y;
    for (int off = 32; off; off >>= 1) {
        s0 += __shfl_down(s0, off);
        s1 += __shfl_down(s1, off);
    }
    if (lane == 0) {
        out[wid * 2 + 0] = s0 + b2[0];
        out[wid * 2 + 1] = s1 + b2[1];
    }
}

extern "C" void kernel_launch(void* const* d_in, const int* in_sizes, int n_in,
                              void* d_out, int out_size, void* d_ws, size_t ws_size,
                              hipStream_t stream) {
    const float* x  = (const float*)d_in[0];
    const int*   ei = (const int*)d_in[1];
    const float* Wl = (const float*)d_in[2];
    const float* bl = (const float*)d_in[3];
    const float* Wr = (const float*)d_in[4];
    const float* W1 = (const float*)d_in[5];
    const float* b1 = (const float*)d_in[6];
    const float* W2 = (const float*)d_in[7];
    const float* b2 = (const float*)d_in[8];
    float* out = (float*)d_out;

    // ---- workspace layout ----
    int* counts  = (int*)d_ws;                      // NN
    int* offsets = counts + NN;                     // NN+1
    int* bsums   = offsets + NN + 1;                // 64
    int* bbase   = bsums + 64;                      // 64
    int* csr     = bbase + 64;                      // NE
    size_t fixed = ((size_t)(NN + NN + 1 + 128 + NE) * sizeof(int) + 255) & ~(size_t)255;
    ushort* xb   = (ushort*)((char*)d_ws + fixed);  // NN*DIM bf16
    ushort* bufA = xb + (size_t)NN * DIM;
    ushort* bufB = bufA + (size_t)NN * DIM;
    ushort* Wlb  = bufB + (size_t)NN * DIM;         // 12*128*128
    ushort* Wrb  = Wlb + (size_t)NL * DIM * DIM;
    ushort* W1b  = Wrb + (size_t)NL * DIM * DIM;    // 128*128

    const int* src = ei;
    const int* dst = ei + NE;

    int ncvt = NX8 + 2 * NW8 + NW18;
    cvt_all<<<(ncvt + 255) / 256, 256, 0, stream>>>(x, Wl, Wr, W1, xb, Wlb, Wrb, W1b);

    const int NB = (NN + 1023) / 1024;   // 49
    hipMemsetAsync(counts, 0, NN * sizeof(int), stream);
    count_kernel<<<(NE + 255) / 256, 256, 0, stream>>>(dst, counts);
    scan1_kernel<<<NB, 1024, 0, stream>>>(counts, offsets, bsums);
    scan2_kernel<<<1, 64, 0, stream>>>(bsums, bbase, NB);
    scan3_kernel<<<(NN + 1 + 255) / 256, 256, 0, stream>>>(offsets, bbase);
    hipMemsetAsync(counts, 0, NN * sizeof(int), stream);
    fill_kernel<<<(NE + 255) / 256, 256, 0, stream>>>(src, dst, offsets, counts, csr);

    static const int AGGRS[NL] = {0, 1, 2, 0, 1, 2, 0, 1, 2, 0, 2, 1};
    const ushort* h = xb;
    dim3 agrd((NN * 64 + 255) / 256);    // 12500 blocks: wave per node
    dim3 ggrd((NN + 127) / 128);         // 391 blocks
    // Two-buffer rotation: layer i gathers h -> buf[i&1], GEMM in-place on buf[i&1].
    for (int i = 0; i < NL; ++i) {
        ushort* aggbuf = (i & 1) ? bufB : bufA;
        if (AGGRS[i] == 0)
            aggregate_kernel<0><<<agrd, 256, 0, stream>>>(h, aggbuf, csr, offsets);
        else if (AGGRS[i] == 1)
            aggregate_kernel<1><<<agrd, 256, 0, stream>>>(h, aggbuf, csr, offsets);
        else
            aggregate_kernel<2><<<agrd, 256, 0, stream>>>(h, aggbuf, csr, offsets);
        gemm_kernel<2><<<ggrd, 256, 0, stream>>>(aggbuf, Wlb + (size_t)i * DIM * DIM, h,
                                                 Wrb + (size_t)i * DIM * DIM,
                                                 bl + (size_t)i * DIM, aggbuf);
        h = aggbuf;
    }
    // final MLP: relu(h@W1^T + b1) -> spare buffer (h ends in bufB), then 128->2 projection
    ushort* h2 = (h == bufB) ? bufA : bufB;
    gemm_kernel<1><<<ggrd, 256, 0, stream>>>(h, W1b, nullptr, nullptr, b1, h2);
    out_kernel<<<agrd, 256, 0, stream>>>(h2, W2, b2, out);
}

// Round 8
// 843.056 us; speedup vs baseline: 1.1892x; 1.1892x over previous
//
#include <hip/hip_runtime.h>
#include <math.h>

#define NN 50000
#define NE 600000
#define DIM 128
#define NL 12

typedef short bf16x8 __attribute__((ext_vector_type(8)));
typedef float f32x4 __attribute__((ext_vector_type(4)));

__device__ __forceinline__ uint f2b_rne(float f) {
    uint u = __float_as_uint(f);
    return (u + 0x7fffu + ((u >> 16) & 1u)) >> 16;
}

// ---------------- fused fp32 -> bf16 convert for all 4 tensors ----------------
#define NX8 (NN * DIM / 8)               // 800000
#define NW8 (NL * DIM * DIM / 8)         // 24576
#define NW18 (DIM * DIM / 8)             // 2048
__global__ void cvt_all(const float* __restrict__ x, const float* __restrict__ Wl,
                        const float* __restrict__ Wr, const float* __restrict__ W1,
                        ushort* __restrict__ xb, ushort* __restrict__ Wlb,
                        ushort* __restrict__ Wrb, ushort* __restrict__ W1b) {
    int i = blockIdx.x * blockDim.x + threadIdx.x;
    const float* in; ushort* out; int off;
    if (i < NX8)                        { in = x;  out = xb;  off = i; }
    else if (i < NX8 + NW8)             { in = Wl; out = Wlb; off = i - NX8; }
    else if (i < NX8 + 2 * NW8)         { in = Wr; out = Wrb; off = i - NX8 - NW8; }
    else if (i < NX8 + 2 * NW8 + NW18)  { in = W1; out = W1b; off = i - NX8 - 2 * NW8; }
    else return;
    const float4* p = reinterpret_cast<const float4*>(in);
    float4 v0 = p[off * 2], v1 = p[off * 2 + 1];
    uint4 o;
    o.x = (f2b_rne(v0.y) << 16) | f2b_rne(v0.x);
    o.y = (f2b_rne(v0.w) << 16) | f2b_rne(v0.z);
    o.z = (f2b_rne(v1.y) << 16) | f2b_rne(v1.x);
    o.w = (f2b_rne(v1.w) << 16) | f2b_rne(v1.z);
    reinterpret_cast<uint4*>(out)[off] = o;
}

// ---------------- CSR build ----------------
__global__ void count_kernel(const int* __restrict__ dst, int* __restrict__ counts) {
    int e = blockIdx.x * blockDim.x + threadIdx.x;
    if (e < NE) atomicAdd(&counts[dst[e]], 1);
}

__global__ __launch_bounds__(1024) void scan1_kernel(const int* __restrict__ counts,
                                                     int* __restrict__ offsets,
                                                     int* __restrict__ bsums) {
    int b = blockIdx.x, t = threadIdx.x;
    int i = b * 1024 + t;
    int lane = t & 63, wid = t >> 6;
    int val = (i < NN) ? counts[i] : 0;
#pragma unroll
    for (int o = 1; o < 64; o <<= 1) {
        int n = __shfl_up(val, o);
        if (lane >= o) val += n;
    }
    __shared__ int ws[16];
    if (lane == 63) ws[wid] = val;
    __syncthreads();
    if (wid == 0 && lane < 16) {
        int s = ws[lane];
#pragma unroll
        for (int o = 1; o < 16; o <<= 1) {
            int n = __shfl_up(s, o);
            if (lane >= o) s += n;
        }
        ws[lane] = s;
    }
    __syncthreads();
    if (wid) val += ws[wid - 1];
    if (i < NN) offsets[i + 1] = val;
    if (t == 1023) bsums[b] = val;
}

__global__ void scan2_kernel(const int* __restrict__ bsums, int* __restrict__ bbase, int nb) {
    int lane = threadIdx.x;
    int v = (lane < nb) ? bsums[lane] : 0;
    int val = v;
#pragma unroll
    for (int o = 1; o < 64; o <<= 1) {
        int n = __shfl_up(val, o);
        if (lane >= o) val += n;
    }
    if (lane < nb) bbase[lane] = val - v;   // exclusive
}

__global__ void scan3_kernel(int* __restrict__ offsets, const int* __restrict__ bbase) {
    int i = blockIdx.x * blockDim.x + threadIdx.x;
    if (i == 0) { offsets[0] = 0; return; }
    if (i <= NN) offsets[i] += bbase[(i - 1) >> 10];
}

__global__ void fill_kernel(const int* __restrict__ src, const int* __restrict__ dst,
                            const int* __restrict__ offsets, int* __restrict__ cursor,
                            int* __restrict__ csr) {
    int e = blockIdx.x * blockDim.x + threadIdx.x;
    if (e < NE) {
        int d = dst[e];
        int p = atomicAdd(&cursor[d], 1);
        csr[offsets[d] + p] = src[e];
    }
}

// ---------------- aggregation: one wave per node, full 256B row per gather ----------------
// 64 lanes x uint (2 bf16) = one row per load; unroll 16 -> up to 16 gathers in flight.
// Wave-uniform predication branch-skips masked slots (no wasted requests).
// AGGR: 0=sum, 1=mean, 2=max
template <int AGGR>
__global__ __launch_bounds__(256) void aggregate_kernel(
    const ushort* __restrict__ h, ushort* __restrict__ agg,
    const int* __restrict__ csr, const int* __restrict__ offsets) {
    int wid = (blockIdx.x * blockDim.x + threadIdx.x) >> 6;
    int l = threadIdx.x & 63;
    if (wid >= NN) return;
    int s0 = offsets[wid], s1 = offsets[wid + 1];
    const uint* hp = reinterpret_cast<const uint*>(h);   // row = 64 uints
    float ax, ay;
    if (AGGR == 2) { ax = ay = -INFINITY; } else { ax = ay = 0.f; }
    for (int e = s0; e < s1; e += 16) {
        uint u[16];
#pragma unroll
        for (int q = 0; q < 16; ++q) {
            if (e + q < s1)                       // wave-uniform: cheap scalar branch
                u[q] = hp[(size_t)csr[e + q] * 64 + l];
        }
#pragma unroll
        for (int q = 0; q < 16; ++q) {
            if (e + q < s1) {
                float fx = __uint_as_float(u[q] << 16);
                float fy = __uint_as_float(u[q] & 0xffff0000u);
                if (AGGR == 2) { ax = fmaxf(ax, fx); ay = fmaxf(ay, fy); }
                else           { ax += fx;           ay += fy; }
            }
        }
    }
    int deg = s1 - s0;
    if (AGGR == 1) {
        float inv = 1.f / (float)(deg > 0 ? deg : 1);
        ax *= inv; ay *= inv;
    }
    if (AGGR == 2 && deg == 0) { ax = ay = 0.f; }
    uint o = (f2b_rne(ay) << 16) | f2b_rne(ax);
    reinterpret_cast<uint*>(agg)[(size_t)wid * 64 + l] = o;
}

// ---------------- MFMA GEMM, LDS-staged W, swapped operands ----------------
// C[n][:] = relu(A1[n] @ Wa^T [+ A2[n] @ Wb^T] + bias)
// Block = 4 waves x 32 rows = 128 rows. W matrices staged once per block into LDS
// (XOR swizzle byte ^= (row&7)<<4 -> ds_read_b128 worst case 2-way = free).
// mfma(W-frag as A, node-frag as B) -> D[m=outcol][n=node]; packed uint2 stores.
// In-place C==A1 safe: wave reads only its own rows, stores after all reads.
template <int NPASS>
__global__ __launch_bounds__(256) void gemm_kernel(
    const ushort* __restrict__ A1, const ushort* __restrict__ Wa,
    const ushort* __restrict__ A2, const ushort* __restrict__ Wb,
    const float* __restrict__ bias, ushort* __restrict__ C) {
    __shared__ ushort Wlds[NPASS][DIM * DIM];     // 32KB per matrix
    int t = threadIdx.x, w = t >> 6, l = t & 63;
    int lr = l & 15, lg = l >> 4;

    // ---- stage W (each thread: 8 x 16B chunks per matrix) ----
#pragma unroll
    for (int pass = 0; pass < NPASS; ++pass) {
        const uint4* Wv = reinterpret_cast<const uint4*>(pass ? Wb : Wa);
        char* base = reinterpret_cast<char*>(Wlds[pass]);
#pragma unroll
        for (int i = 0; i < 8; ++i) {
            int chunk = t + i * 256;              // 16B chunk id, 0..2047
            uint4 v = Wv[chunk];
            int byte = chunk << 4;
            int row = byte >> 8;
            *reinterpret_cast<uint4*>(base + (byte ^ ((row & 7) << 4))) = v;
        }
    }
    __syncthreads();

    int row0 = blockIdx.x * 128 + w * 32;
    f32x4 acc[2][8];
#pragma unroll
    for (int rf = 0; rf < 2; ++rf)
#pragma unroll
        for (int c = 0; c < 8; ++c) acc[rf][c] = (f32x4){0.f, 0.f, 0.f, 0.f};
    int grow0 = min(row0 + lr, NN - 1);        // clamp; OOB discarded at store
    int grow1 = min(row0 + 16 + lr, NN - 1);

#pragma unroll
    for (int pass = 0; pass < NPASS; ++pass) {
        const ushort* A = pass ? A2 : A1;
        const char* wbase = reinterpret_cast<const char*>(Wlds[pass]);
#pragma unroll
        for (int kk = 0; kk < 4; ++kk) {
            int ko = kk * 32 + lg * 8;
            bf16x8 nf0 = *reinterpret_cast<const bf16x8*>(A + (size_t)grow0 * DIM + ko);
            bf16x8 nf1 = *reinterpret_cast<const bf16x8*>(A + (size_t)grow1 * DIM + ko);
#pragma unroll
            for (int c = 0; c < 8; ++c) {
                int wbyte = (((c * 16 + lr) << 8) + (ko << 1)) ^ ((lr & 7) << 4);
                bf16x8 wf = *reinterpret_cast<const bf16x8*>(wbase + wbyte);
                acc[0][c] = __builtin_amdgcn_mfma_f32_16x16x32_bf16(wf, nf0, acc[0][c], 0, 0, 0);
                acc[1][c] = __builtin_amdgcn_mfma_f32_16x16x32_bf16(wf, nf1, acc[1][c], 0, 0, 0);
            }
        }
    }
#pragma unroll
    for (int rf = 0; rf < 2; ++rf) {
        int orow = row0 + rf * 16 + lr;
        if (orow < NN) {
#pragma unroll
            for (int c = 0; c < 8; ++c) {
                int col0 = c * 16 + lg * 4;
                float4 b4 = *reinterpret_cast<const float4*>(bias + col0);
                float v0 = fmaxf(acc[rf][c][0] + b4.x, 0.f);
                float v1 = fmaxf(acc[rf][c][1] + b4.y, 0.f);
                float v2 = fmaxf(acc[rf][c][2] + b4.z, 0.f);
                float v3 = fmaxf(acc[rf][c][3] + b4.w, 0.f);
                uint2 o;
                o.x = (f2b_rne(v1) << 16) | f2b_rne(v0);
                o.y = (f2b_rne(v3) << 16) | f2b_rne(v2);
                *reinterpret_cast<uint2*>(C + (size_t)orow * DIM + col0) = o;
            }
        }
    }
}

// ---------------- final 128 -> 2 projection ----------------
__global__ void out_kernel(const ushort* __restrict__ h2, const float* __restrict__ W2,
                           const float* __restrict__ b2, float* __restrict__ out) {
    int wid = (blockIdx.x * blockDim.x + threadIdx.x) >> 6;
    int lane = threadIdx.x & 63;
    if (wid >= NN) return;
    uint u = reinterpret_cast<const uint*>(h2)[(size_t)wid * 64 + lane];
    float vx = __uint_as_float(u << 16), vy = __uint_as_float(u & 0xffff0000u);
    float2 w0 = *reinterpret_cast<const float2*>(W2 + lane * 2);
    float2 w1 = *reinterpret_cast<const float2*>(W2 + DIM + lane * 2);
    float s0 = vx * w0.x + vy * w0.y;
    float s1 = vx * w1.x + vy * w1.y;
    for (int off = 32; off; off >>= 1) {
        s0 += __shfl_down(s0, off);
        s1 += __shfl_down(s1, off);
    }
    if (lane == 0) {
        out[wid * 2 + 0] = s0 + b2[0];
        out[wid * 2 + 1] = s1 + b2[1];
    }
}

extern "C" void kernel_launch(void* const* d_in, const int* in_sizes, int n_in,
                              void* d_out, int out_size, void* d_ws, size_t ws_size,
                              hipStream_t stream) {
    const float* x  = (const float*)d_in[0];
    const int*   ei = (const int*)d_in[1];
    const float* Wl = (const float*)d_in[2];
    const float* bl = (const float*)d_in[3];
    const float* Wr = (const float*)d_in[4];
    const float* W1 = (const float*)d_in[5];
    const float* b1 = (const float*)d_in[6];
    const float* W2 = (const float*)d_in[7];
    const float* b2 = (const float*)d_in[8];
    float* out = (float*)d_out;

    // ---- workspace layout ----
    int* counts  = (int*)d_ws;                      // NN
    int* offsets = counts + NN;                     // NN+1
    int* bsums   = offsets + NN + 1;                // 64
    int* bbase   = bsums + 64;                      // 64
    int* csr     = bbase + 64;                      // NE
    size_t fixed = ((size_t)(NN + NN + 1 + 128 + NE) * sizeof(int) + 255) & ~(size_t)255;
    ushort* xb   = (ushort*)((char*)d_ws + fixed);  // NN*DIM bf16
    ushort* bufA = xb + (size_t)NN * DIM;
    ushort* bufB = bufA + (size_t)NN * DIM;
    ushort* Wlb  = bufB + (size_t)NN * DIM;         // 12*128*128
    ushort* Wrb  = Wlb + (size_t)NL * DIM * DIM;
    ushort* W1b  = Wrb + (size_t)NL * DIM * DIM;    // 128*128

    const int* src = ei;
    const int* dst = ei + NE;

    int ncvt = NX8 + 2 * NW8 + NW18;
    cvt_all<<<(ncvt + 255) / 256, 256, 0, stream>>>(x, Wl, Wr, W1, xb, Wlb, Wrb, W1b);

    const int NB = (NN + 1023) / 1024;   // 49
    hipMemsetAsync(counts, 0, NN * sizeof(int), stream);
    count_kernel<<<(NE + 255) / 256, 256, 0, stream>>>(dst, counts);
    scan1_kernel<<<NB, 1024, 0, stream>>>(counts, offsets, bsums);
    scan2_kernel<<<1, 64, 0, stream>>>(bsums, bbase, NB);
    scan3_kernel<<<(NN + 1 + 255) / 256, 256, 0, stream>>>(offsets, bbase);
    hipMemsetAsync(counts, 0, NN * sizeof(int), stream);
    fill_kernel<<<(NE + 255) / 256, 256, 0, stream>>>(src, dst, offsets, counts, csr);

    static const int AGGRS[NL] = {0, 1, 2, 0, 1, 2, 0, 1, 2, 0, 2, 1};
    const ushort* h = xb;
    dim3 agrd((NN * 64 + 255) / 256);    // 12500 blocks: wave per node
    dim3 ggrd((NN + 127) / 128);         // 391 blocks
    // Two-buffer rotation: layer i gathers h -> buf[i&1], GEMM in-place on buf[i&1].
    for (int i = 0; i < NL; ++i) {
        ushort* aggbuf = (i & 1) ? bufB : bufA;
        if (AGGRS[i] == 0)
            aggregate_kernel<0><<<agrd, 256, 0, stream>>>(h, aggbuf, csr, offsets);
        else if (AGGRS[i] == 1)
            aggregate_kernel<1><<<agrd, 256, 0, stream>>>(h, aggbuf, csr, offsets);
        else
            aggregate_kernel<2><<<agrd, 256, 0, stream>>>(h, aggbuf, csr, offsets);
        gemm_kernel<2><<<ggrd, 256, 0, stream>>>(aggbuf, Wlb + (size_t)i * DIM * DIM, h,
                                                 Wrb + (size_t)i * DIM * DIM,
                                                 bl + (size_t)i * DIM, aggbuf);
        h = aggbuf;
    }
    // final MLP: relu(h@W1^T + b1) -> spare buffer (h ends in bufB), then 128->2 projection
    ushort* h2 = (h == bufB) ? bufA : bufB;
    gemm_kernel<1><<<ggrd, 256, 0, stream>>>(h, W1b, nullptr, nullptr, b1, h2);
    out_kernel<<<agrd, 256, 0, stream>>>(h2, W2, b2, out);
}

// Round 9
// 627.330 us; speedup vs baseline: 1.5982x; 1.3439x over previous
//
#include <hip/hip_runtime.h>
#include <math.h>

#define NN 50000
#define NE 600000
#define DIM 128
#define NL 12

typedef short bf16x8 __attribute__((ext_vector_type(8)));
typedef float f32x4 __attribute__((ext_vector_type(4)));

__device__ __forceinline__ uint f2b_rne(float f) {
    uint u = __float_as_uint(f);
    return (u + 0x7fffu + ((u >> 16) & 1u)) >> 16;
}

// ---------------- fused fp32 -> bf16 convert for all 4 tensors ----------------
#define NX8 (NN * DIM / 8)               // 800000
#define NW8 (NL * DIM * DIM / 8)         // 24576
#define NW18 (DIM * DIM / 8)             // 2048
__global__ void cvt_all(const float* __restrict__ x, const float* __restrict__ Wl,
                        const float* __restrict__ Wr, const float* __restrict__ W1,
                        ushort* __restrict__ xb, ushort* __restrict__ Wlb,
                        ushort* __restrict__ Wrb, ushort* __restrict__ W1b) {
    int i = blockIdx.x * blockDim.x + threadIdx.x;
    const float* in; ushort* out; int off;
    if (i < NX8)                        { in = x;  out = xb;  off = i; }
    else if (i < NX8 + NW8)             { in = Wl; out = Wlb; off = i - NX8; }
    else if (i < NX8 + 2 * NW8)         { in = Wr; out = Wrb; off = i - NX8 - NW8; }
    else if (i < NX8 + 2 * NW8 + NW18)  { in = W1; out = W1b; off = i - NX8 - 2 * NW8; }
    else return;
    const float4* p = reinterpret_cast<const float4*>(in);
    float4 v0 = p[off * 2], v1 = p[off * 2 + 1];
    uint4 o;
    o.x = (f2b_rne(v0.y) << 16) | f2b_rne(v0.x);
    o.y = (f2b_rne(v0.w) << 16) | f2b_rne(v0.z);
    o.z = (f2b_rne(v1.y) << 16) | f2b_rne(v1.x);
    o.w = (f2b_rne(v1.w) << 16) | f2b_rne(v1.z);
    reinterpret_cast<uint4*>(out)[off] = o;
}

// ---------------- CSR build ----------------
__global__ void count_kernel(const int* __restrict__ dst, int* __restrict__ counts) {
    int e = blockIdx.x * blockDim.x + threadIdx.x;
    if (e < NE) atomicAdd(&counts[dst[e]], 1);
}

__global__ __launch_bounds__(1024) void scan1_kernel(const int* __restrict__ counts,
                                                     int* __restrict__ offsets,
                                                     int* __restrict__ bsums) {
    int b = blockIdx.x, t = threadIdx.x;
    int i = b * 1024 + t;
    int lane = t & 63, wid = t >> 6;
    int val = (i < NN) ? counts[i] : 0;
#pragma unroll
    for (int o = 1; o < 64; o <<= 1) {
        int n = __shfl_up(val, o);
        if (lane >= o) val += n;
    }
    __shared__ int ws[16];
    if (lane == 63) ws[wid] = val;
    __syncthreads();
    if (wid == 0 && lane < 16) {
        int s = ws[lane];
#pragma unroll
        for (int o = 1; o < 16; o <<= 1) {
            int n = __shfl_up(s, o);
            if (lane >= o) s += n;
        }
        ws[lane] = s;
    }
    __syncthreads();
    if (wid) val += ws[wid - 1];
    if (i < NN) offsets[i + 1] = val;
    if (t == 1023) bsums[b] = val;
}

__global__ void scan2_kernel(const int* __restrict__ bsums, int* __restrict__ bbase, int nb) {
    int lane = threadIdx.x;
    int v = (lane < nb) ? bsums[lane] : 0;
    int val = v;
#pragma unroll
    for (int o = 1; o < 64; o <<= 1) {
        int n = __shfl_up(val, o);
        if (lane >= o) val += n;
    }
    if (lane < nb) bbase[lane] = val - v;   // exclusive
}

__global__ void scan3_kernel(int* __restrict__ offsets, const int* __restrict__ bbase) {
    int i = blockIdx.x * blockDim.x + threadIdx.x;
    if (i == 0) { offsets[0] = 0; return; }
    if (i <= NN) offsets[i] += bbase[(i - 1) >> 10];
}

__global__ void fill_kernel(const int* __restrict__ src, const int* __restrict__ dst,
                            const int* __restrict__ offsets, int* __restrict__ cursor,
                            int* __restrict__ csr) {
    int e = blockIdx.x * blockDim.x + threadIdx.x;
    if (e < NE) {
        int d = dst[e];
        int p = atomicAdd(&cursor[d], 1);
        csr[offsets[d] + p] = src[e];
    }
}

// ---------------- aggregation: one wave per node, full 256B row per gather ----------------
// 16 UNCONDITIONAL gathers per batch (tail slots clamp to last edge -> L1-hit dup),
// sched_barrier pins: all loads issue back-to-back, ONE waitcnt, then math.
// This prevents the compiler from guard-merging load with use (round-8 bug: VGPR=16,
// ~1 load in flight -> serialized miss latency).
// AGGR: 0=sum, 1=mean, 2=max
template <int AGGR>
__global__ __launch_bounds__(256) void aggregate_kernel(
    const ushort* __restrict__ h, ushort* __restrict__ agg,
    const int* __restrict__ csr, const int* __restrict__ offsets) {
    int wid = (blockIdx.x * blockDim.x + threadIdx.x) >> 6;
    int l = threadIdx.x & 63;
    if (wid >= NN) return;
    int s0 = offsets[wid], s1 = offsets[wid + 1];
    const uint* hp = reinterpret_cast<const uint*>(h);   // row = 64 uints
    float ax, ay;
    if (AGGR == 2) { ax = ay = -INFINITY; } else { ax = ay = 0.f; }
    for (int e = s0; e < s1; e += 16) {
        int rem = s1 - e;                    // >=1 inside loop
        uint u[16];
#pragma unroll
        for (int q = 0; q < 16; ++q) {
            int ee = (q < rem) ? e + q : s1 - 1;     // clamp: unconditional load
            u[q] = hp[(size_t)csr[ee] * 64 + l];
        }
        __builtin_amdgcn_sched_barrier(0);   // keep all 16 loads issued before any use
#pragma unroll
        for (int q = 0; q < 16; ++q) {
            if (q < rem) {
                float fx = __uint_as_float(u[q] << 16);
                float fy = __uint_as_float(u[q] & 0xffff0000u);
                if (AGGR == 2) { ax = fmaxf(ax, fx); ay = fmaxf(ay, fy); }
                else           { ax += fx;           ay += fy; }
            }
        }
    }
    int deg = s1 - s0;
    if (AGGR == 1) {
        float inv = 1.f / (float)(deg > 0 ? deg : 1);
        ax *= inv; ay *= inv;
    }
    if (AGGR == 2 && deg == 0) { ax = ay = 0.f; }
    uint o = (f2b_rne(ay) << 16) | f2b_rne(ax);
    reinterpret_cast<uint*>(agg)[(size_t)wid * 64 + l] = o;
}

// ---------------- MFMA GEMM, LDS-staged W, swapped operands ----------------
// C[n][:] = relu(A1[n] @ Wa^T [+ A2[n] @ Wb^T] + bias)
// Block = 4 waves x 32 rows = 128 rows. W matrices staged once per block into LDS
// (XOR swizzle byte ^= (row&7)<<4 -> ds_read_b128 worst case 2-way = free).
// mfma(W-frag as A, node-frag as B) -> D[m=outcol][n=node]; packed uint2 stores.
// In-place C==A1 safe: wave reads only its own rows, stores after all reads.
template <int NPASS>
__global__ __launch_bounds__(256) void gemm_kernel(
    const ushort* __restrict__ A1, const ushort* __restrict__ Wa,
    const ushort* __restrict__ A2, const ushort* __restrict__ Wb,
    const float* __restrict__ bias, ushort* __restrict__ C) {
    __shared__ ushort Wlds[NPASS][DIM * DIM];     // 32KB per matrix
    int t = threadIdx.x, w = t >> 6, l = t & 63;
    int lr = l & 15, lg = l >> 4;

    // ---- stage W (each thread: 8 x 16B chunks per matrix) ----
#pragma unroll
    for (int pass = 0; pass < NPASS; ++pass) {
        const uint4* Wv = reinterpret_cast<const uint4*>(pass ? Wb : Wa);
        char* base = reinterpret_cast<char*>(Wlds[pass]);
#pragma unroll
        for (int i = 0; i < 8; ++i) {
            int chunk = t + i * 256;              // 16B chunk id, 0..2047
            uint4 v = Wv[chunk];
            int byte = chunk << 4;
            int row = byte >> 8;
            *reinterpret_cast<uint4*>(base + (byte ^ ((row & 7) << 4))) = v;
        }
    }
    __syncthreads();

    int row0 = blockIdx.x * 128 + w * 32;
    f32x4 acc[2][8];
#pragma unroll
    for (int rf = 0; rf < 2; ++rf)
#pragma unroll
        for (int c = 0; c < 8; ++c) acc[rf][c] = (f32x4){0.f, 0.f, 0.f, 0.f};
    int grow0 = min(row0 + lr, NN - 1);        // clamp; OOB discarded at store
    int grow1 = min(row0 + 16 + lr, NN - 1);

#pragma unroll
    for (int pass = 0; pass < NPASS; ++pass) {
        const ushort* A = pass ? A2 : A1;
        const char* wbase = reinterpret_cast<const char*>(Wlds[pass]);
#pragma unroll
        for (int kk = 0; kk < 4; ++kk) {
            int ko = kk * 32 + lg * 8;
            bf16x8 nf0 = *reinterpret_cast<const bf16x8*>(A + (size_t)grow0 * DIM + ko);
            bf16x8 nf1 = *reinterpret_cast<const bf16x8*>(A + (size_t)grow1 * DIM + ko);
#pragma unroll
            for (int c = 0; c < 8; ++c) {
                int wbyte = (((c * 16 + lr) << 8) + (ko << 1)) ^ ((lr & 7) << 4);
                bf16x8 wf = *reinterpret_cast<const bf16x8*>(wbase + wbyte);
                acc[0][c] = __builtin_amdgcn_mfma_f32_16x16x32_bf16(wf, nf0, acc[0][c], 0, 0, 0);
                acc[1][c] = __builtin_amdgcn_mfma_f32_16x16x32_bf16(wf, nf1, acc[1][c], 0, 0, 0);
            }
        }
    }
#pragma unroll
    for (int rf = 0; rf < 2; ++rf) {
        int orow = row0 + rf * 16 + lr;
        if (orow < NN) {
#pragma unroll
            for (int c = 0; c < 8; ++c) {
                int col0 = c * 16 + lg * 4;
                float4 b4 = *reinterpret_cast<const float4*>(bias + col0);
                float v0 = fmaxf(acc[rf][c][0] + b4.x, 0.f);
                float v1 = fmaxf(acc[rf][c][1] + b4.y, 0.f);
                float v2 = fmaxf(acc[rf][c][2] + b4.z, 0.f);
                float v3 = fmaxf(acc[rf][c][3] + b4.w, 0.f);
                uint2 o;
                o.x = (f2b_rne(v1) << 16) | f2b_rne(v0);
                o.y = (f2b_rne(v3) << 16) | f2b_rne(v2);
                *reinterpret_cast<uint2*>(C + (size_t)orow * DIM + col0) = o;
            }
        }
    }
}

// ---------------- final 128 -> 2 projection ----------------
__global__ void out_kernel(const ushort* __restrict__ h2, const float* __restrict__ W2,
                           const float* __restrict__ b2, float* __restrict__ out) {
    int wid = (blockIdx.x * blockDim.x + threadIdx.x) >> 6;
    int lane = threadIdx.x & 63;
    if (wid >= NN) return;
    uint u = reinterpret_cast<const uint*>(h2)[(size_t)wid * 64 + lane];
    float vx = __uint_as_float(u << 16), vy = __uint_as_float(u & 0xffff0000u);
    float2 w0 = *reinterpret_cast<const float2*>(W2 + lane * 2);
    float2 w1 = *reinterpret_cast<const float2*>(W2 + DIM + lane * 2);
    float s0 = vx * w0.x + vy * w0.y;
    float s1 = vx * w1.x + vy * w1.y;
    for (int off = 32; off; off >>= 1) {
        s0 += __shfl_down(s0, off);
        s1 += __shfl_down(s1, off);
    }
    if (lane == 0) {
        out[wid * 2 + 0] = s0 + b2[0];
        out[wid * 2 + 1] = s1 + b2[1];
    }
}

extern "C" void kernel_launch(void* const* d_in, const int* in_sizes, int n_in,
                              void* d_out, int out_size, void* d_ws, size_t ws_size,
                              hipStream_t stream) {
    const float* x  = (const float*)d_in[0];
    const int*   ei = (const int*)d_in[1];
    const float* Wl = (const float*)d_in[2];
    const float* bl = (const float*)d_in[3];
    const float* Wr = (const float*)d_in[4];
    const float* W1 = (const float*)d_in[5];
    const float* b1 = (const float*)d_in[6];
    const float* W2 = (const float*)d_in[7];
    const float* b2 = (const float*)d_in[8];
    float* out = (float*)d_out;

    // ---- workspace layout ----
    int* counts  = (int*)d_ws;                      // NN
    int* offsets = counts + NN;                     // NN+1
    int* bsums   = offsets + NN + 1;                // 64
    int* bbase   = bsums + 64;                      // 64
    int* csr     = bbase + 64;                      // NE
    size_t fixed = ((size_t)(NN + NN + 1 + 128 + NE) * sizeof(int) + 255) & ~(size_t)255;
    ushort* xb   = (ushort*)((char*)d_ws + fixed);  // NN*DIM bf16
    ushort* bufA = xb + (size_t)NN * DIM;
    ushort* bufB = bufA + (size_t)NN * DIM;
    ushort* Wlb  = bufB + (size_t)NN * DIM;         // 12*128*128
    ushort* Wrb  = Wlb + (size_t)NL * DIM * DIM;
    ushort* W1b  = Wrb + (size_t)NL * DIM * DIM;    // 128*128

    const int* src = ei;
    const int* dst = ei + NE;

    int ncvt = NX8 + 2 * NW8 + NW18;
    cvt_all<<<(ncvt + 255) / 256, 256, 0, stream>>>(x, Wl, Wr, W1, xb, Wlb, Wrb, W1b);

    const int NB = (NN + 1023) / 1024;   // 49
    hipMemsetAsync(counts, 0, NN * sizeof(int), stream);
    count_kernel<<<(NE + 255) / 256, 256, 0, stream>>>(dst, counts);
    scan1_kernel<<<NB, 1024, 0, stream>>>(counts, offsets, bsums);
    scan2_kernel<<<1, 64, 0, stream>>>(bsums, bbase, NB);
    scan3_kernel<<<(NN + 1 + 255) / 256, 256, 0, stream>>>(offsets, bbase);
    hipMemsetAsync(counts, 0, NN * sizeof(int), stream);
    fill_kernel<<<(NE + 255) / 256, 256, 0, stream>>>(src, dst, offsets, counts, csr);

    static const int AGGRS[NL] = {0, 1, 2, 0, 1, 2, 0, 1, 2, 0, 2, 1};
    const ushort* h = xb;
    dim3 agrd((NN * 64 + 255) / 256);    // 12500 blocks: wave per node
    dim3 ggrd((NN + 127) / 128);         // 391 blocks
    // Two-buffer rotation: layer i gathers h -> buf[i&1], GEMM in-place on buf[i&1].
    for (int i = 0; i < NL; ++i) {
        ushort* aggbuf = (i & 1) ? bufB : bufA;
        if (AGGRS[i] == 0)
            aggregate_kernel<0><<<agrd, 256, 0, stream>>>(h, aggbuf, csr, offsets);
        else if (AGGRS[i] == 1)
            aggregate_kernel<1><<<agrd, 256, 0, stream>>>(h, aggbuf, csr, offsets);
        else
            aggregate_kernel<2><<<agrd, 256, 0, stream>>>(h, aggbuf, csr, offsets);
        gemm_kernel<2><<<ggrd, 256, 0, stream>>>(aggbuf, Wlb + (size_t)i * DIM * DIM, h,
                                                 Wrb + (size_t)i * DIM * DIM,
                                                 bl + (size_t)i * DIM, aggbuf);
        h = aggbuf;
    }
    // final MLP: relu(h@W1^T + b1) -> spare buffer (h ends in bufB), then 128->2 projection
    ushort* h2 = (h == bufB) ? bufA : bufB;
    gemm_kernel<1><<<ggrd, 256, 0, stream>>>(h, W1b, nullptr, nullptr, b1, h2);
    out_kernel<<<agrd, 256, 0, stream>>>(h2, W2, b2, out);
}

// Round 11
// 614.715 us; speedup vs baseline: 1.6310x; 1.0205x over previous
//
#include <hip/hip_runtime.h>
#include <math.h>

#define NN 50000
#define NE 600000
#define DIM 128
#define NL 12

typedef short bf16x8 __attribute__((ext_vector_type(8)));
typedef float f32x4 __attribute__((ext_vector_type(4)));

__device__ __forceinline__ uint f2b_rne(float f) {
    uint u = __float_as_uint(f);
    return (u + 0x7fffu + ((u >> 16) & 1u)) >> 16;
}

#define NX8 (NN * DIM / 8)               // 800000
#define NW8 (NL * DIM * DIM / 8)         // 24576
#define NW18 (DIM * DIM / 8)             // 2048
#define NCVT (NX8 + 2 * NW8 + NW18)      // 851200

// ---------------- prep: fused bf16 convert (all tensors) + degree count ----------------
__global__ void prep_kernel(const float* __restrict__ x, const float* __restrict__ Wl,
                            const float* __restrict__ Wr, const float* __restrict__ W1,
                            ushort* __restrict__ xb, ushort* __restrict__ Wlb,
                            ushort* __restrict__ Wrb, ushort* __restrict__ W1b,
                            const int* __restrict__ dst, int* __restrict__ counts) {
    int i = blockIdx.x * blockDim.x + threadIdx.x;
    if (i < NE) atomicAdd(&counts[dst[i]], 1);
    const float* in; ushort* out; int off;
    if (i < NX8)                        { in = x;  out = xb;  off = i; }
    else if (i < NX8 + NW8)             { in = Wl; out = Wlb; off = i - NX8; }
    else if (i < NX8 + 2 * NW8)         { in = Wr; out = Wrb; off = i - NX8 - NW8; }
    else if (i < NCVT)                  { in = W1; out = W1b; off = i - NX8 - 2 * NW8; }
    else return;
    const float4* p = reinterpret_cast<const float4*>(in);
    float4 v0 = p[off * 2], v1 = p[off * 2 + 1];
    uint4 o;
    o.x = (f2b_rne(v0.y) << 16) | f2b_rne(v0.x);
    o.y = (f2b_rne(v0.w) << 16) | f2b_rne(v0.z);
    o.z = (f2b_rne(v1.y) << 16) | f2b_rne(v1.x);
    o.w = (f2b_rne(v1.w) << 16) | f2b_rne(v1.z);
    reinterpret_cast<uint4*>(out)[off] = o;
}

// ---------------- CSR build ----------------
__global__ __launch_bounds__(1024) void scan1_kernel(const int* __restrict__ counts,
                                                     int* __restrict__ offsets,
                                                     int* __restrict__ bsums) {
    int b = blockIdx.x, t = threadIdx.x;
    int i = b * 1024 + t;
    int lane = t & 63, wid = t >> 6;
    int val = (i < NN) ? counts[i] : 0;
#pragma unroll
    for (int o = 1; o < 64; o <<= 1) {
        int n = __shfl_up(val, o);
        if (lane >= o) val += n;
    }
    __shared__ int ws[16];
    if (lane == 63) ws[wid] = val;
    __syncthreads();
    if (wid == 0 && lane < 16) {
        int s = ws[lane];
#pragma unroll
        for (int o = 1; o < 16; o <<= 1) {
            int n = __shfl_up(s, o);
            if (lane >= o) s += n;
        }
        ws[lane] = s;
    }
    __syncthreads();
    if (wid) val += ws[wid - 1];
    if (i < NN) offsets[i + 1] = val;
    if (t == 1023) bsums[b] = val;
}

__global__ void scan2_kernel(const int* __restrict__ bsums, int* __restrict__ bbase, int nb) {
    int lane = threadIdx.x;
    int v = (lane < nb) ? bsums[lane] : 0;
    int val = v;
#pragma unroll
    for (int o = 1; o < 64; o <<= 1) {
        int n = __shfl_up(val, o);
        if (lane >= o) val += n;
    }
    if (lane < nb) bbase[lane] = val - v;   // exclusive
}

__global__ void scan3_kernel(int* __restrict__ offsets, const int* __restrict__ bbase) {
    int i = blockIdx.x * blockDim.x + threadIdx.x;
    if (i == 0) { offsets[0] = 0; return; }
    if (i <= NN) offsets[i] += bbase[(i - 1) >> 10];
}

__global__ void fill_kernel(const int* __restrict__ src, const int* __restrict__ dst,
                            const int* __restrict__ offsets, int* __restrict__ cursor,
                            int* __restrict__ csr) {
    int e = blockIdx.x * blockDim.x + threadIdx.x;
    if (e < NE) {
        int d = dst[e];
        int p = atomicAdd(&cursor[d], 1);
        csr[offsets[d] + p] = src[e];
    }
}

// ---------------- aggregation: one wave per node, 16 unconditional gathers in flight ------
// Clamped-index unconditional loads + sched_barrier keep 16 loads outstanding
// (round-8 lesson: guarded loads get sunk next to their use -> serialized latency).
// AGGR: 0=sum, 1=mean, 2=max
template <int AGGR>
__global__ __launch_bounds__(256) void aggregate_kernel(
    const ushort* __restrict__ h, ushort* __restrict__ agg,
    const int* __restrict__ csr, const int* __restrict__ offsets) {
    int wid = (blockIdx.x * blockDim.x + threadIdx.x) >> 6;
    int l = threadIdx.x & 63;
    if (wid >= NN) return;
    int s0 = offsets[wid], s1 = offsets[wid + 1];
    const uint* hp = reinterpret_cast<const uint*>(h);   // row = 64 uints
    float ax, ay;
    if (AGGR == 2) { ax = ay = -INFINITY; } else { ax = ay = 0.f; }
    for (int e = s0; e < s1; e += 16) {
        int rem = s1 - e;                    // >=1 inside loop
        uint u[16];
#pragma unroll
        for (int q = 0; q < 16; ++q) {
            int ee = (q < rem) ? e + q : s1 - 1;      // clamp: unconditional load
            uint off = (uint)csr[ee] * 64u + (uint)l; // 32-bit element offset
            u[q] = hp[off];
        }
        __builtin_amdgcn_sched_barrier(0);   // all 16 loads issued before any use
#pragma unroll
        for (int q = 0; q < 16; ++q) {
            if (q < rem) {
                float fx = __uint_as_float(u[q] << 16);
                float fy = __uint_as_float(u[q] & 0xffff0000u);
                if (AGGR == 2) { ax = fmaxf(ax, fx); ay = fmaxf(ay, fy); }
                else           { ax += fx;           ay += fy; }
            }
        }
    }
    int deg = s1 - s0;
    if (AGGR == 1) {
        float inv = 1.f / (float)(deg > 0 ? deg : 1);
        ax *= inv; ay *= inv;
    }
    if (AGGR == 2 && deg == 0) { ax = ay = 0.f; }
    uint o = (f2b_rne(ay) << 16) | f2b_rne(ax);
    reinterpret_cast<uint*>(agg)[(uint)wid * 64u + (uint)l] = o;
}

// ---------------- MFMA GEMM, LDS-staged W, swapped operands, NO aliasing ----------------
// C[n][:] = relu(A1[n] @ Wa^T [+ A2[n] @ Wb^T] + bias); C is a DISTINCT buffer
// (3-buffer rotation in the driver — restrict contracts hold, no in-place UB).
// Block = 4 waves x 32 rows = 128 rows. W staged to LDS, XOR swizzle byte^=(row&7)<<4.
// mfma(W-frag as A, node-frag as B) -> D[m=outcol][n=node]; packed uint2 stores.
template <int NPASS>
__global__ __launch_bounds__(256) void gemm_kernel(
    const ushort* __restrict__ A1, const ushort* __restrict__ Wa,
    const ushort* __restrict__ A2, const ushort* __restrict__ Wb,
    const float* __restrict__ bias, ushort* __restrict__ C) {
    __shared__ ushort Wlds[NPASS][DIM * DIM];     // 32KB per matrix
    int t = threadIdx.x, w = t >> 6, l = t & 63;
    int lr = l & 15, lg = l >> 4;

    // ---- stage W (each thread: 8 x 16B chunks per matrix), XOR-swizzled ----
#pragma unroll
    for (int pass = 0; pass < NPASS; ++pass) {
        const uint4* Wv = reinterpret_cast<const uint4*>(pass ? Wb : Wa);
        char* base = reinterpret_cast<char*>(Wlds[pass]);
#pragma unroll
        for (int i = 0; i < 8; ++i) {
            int chunk = t + i * 256;              // 16B chunk id, 0..2047
            uint4 v = Wv[chunk];
            int byte = chunk << 4;
            int row = byte >> 8;
            *reinterpret_cast<uint4*>(base + (byte ^ ((row & 7) << 4))) = v;
        }
    }
    __syncthreads();

    int row0 = blockIdx.x * 128 + w * 32;
    f32x4 acc[2][8];
#pragma unroll
    for (int rf = 0; rf < 2; ++rf)
#pragma unroll
        for (int c = 0; c < 8; ++c) acc[rf][c] = (f32x4){0.f, 0.f, 0.f, 0.f};
    int grow0 = min(row0 + lr, NN - 1);        // clamp; OOB discarded at store
    int grow1 = min(row0 + 16 + lr, NN - 1);

#pragma unroll
    for (int pass = 0; pass < NPASS; ++pass) {
        const ushort* A = pass ? A2 : A1;
        const char* wbase = reinterpret_cast<const char*>(Wlds[pass]);
#pragma unroll
        for (int kk = 0; kk < 4; ++kk) {
            int ko = kk * 32 + lg * 8;
            bf16x8 nf0 = *reinterpret_cast<const bf16x8*>(A + (size_t)grow0 * DIM + ko);
            bf16x8 nf1 = *reinterpret_cast<const bf16x8*>(A + (size_t)grow1 * DIM + ko);
#pragma unroll
            for (int c = 0; c < 8; ++c) {
                int wbyte = (((c * 16 + lr) << 8) + (ko << 1)) ^ ((lr & 7) << 4);
                bf16x8 wf = *reinterpret_cast<const bf16x8*>(wbase + wbyte);
                acc[0][c] = __builtin_amdgcn_mfma_f32_16x16x32_bf16(wf, nf0, acc[0][c], 0, 0, 0);
                acc[1][c] = __builtin_amdgcn_mfma_f32_16x16x32_bf16(wf, nf1, acc[1][c], 0, 0, 0);
            }
        }
    }
#pragma unroll
    for (int rf = 0; rf < 2; ++rf) {
        int orow = row0 + rf * 16 + lr;
        if (orow < NN) {
#pragma unroll
            for (int c = 0; c < 8; ++c) {
                int col0 = c * 16 + lg * 4;
                float4 b4 = *reinterpret_cast<const float4*>(bias + col0);
                float v0 = fmaxf(acc[rf][c][0] + b4.x, 0.f);
                float v1 = fmaxf(acc[rf][c][1] + b4.y, 0.f);
                float v2 = fmaxf(acc[rf][c][2] + b4.z, 0.f);
                float v3 = fmaxf(acc[rf][c][3] + b4.w, 0.f);
                uint2 o;
                o.x = (f2b_rne(v1) << 16) | f2b_rne(v0);
                o.y = (f2b_rne(v3) << 16) | f2b_rne(v2);
                *reinterpret_cast<uint2*>(C + (size_t)orow * DIM + col0) = o;
            }
        }
    }
}

// ---------------- final 128 -> 2 projection ----------------
__global__ void out_kernel(const ushort* __restrict__ h2, const float* __restrict__ W2,
                           const float* __restrict__ b2, float* __restrict__ out) {
    int wid = (blockIdx.x * blockDim.x + threadIdx.x) >> 6;
    int lane = threadIdx.x & 63;
    if (wid >= NN) return;
    uint u = reinterpret_cast<const uint*>(h2)[(uint)wid * 64u + (uint)lane];
    float vx = __uint_as_float(u << 16), vy = __uint_as_float(u & 0xffff0000u);
    float2 w0 = *reinterpret_cast<const float2*>(W2 + lane * 2);
    float2 w1 = *reinterpret_cast<const float2*>(W2 + DIM + lane * 2);
    float s0 = vx * w0.x + vy * w0.y;
    float s1 = vx * w1.x + vy * w1.y;
    for (int off = 32; off; off >>= 1) {
        s0 += __shfl_down(s0, off);
        s1 += __shfl_down(s1, off);
    }
    if (lane == 0) {
        out[wid * 2 + 0] = s0 + b2[0];
        out[wid * 2 + 1] = s1 + b2[1];
    }
}

extern "C" void kernel_launch(void* const* d_in, const int* in_sizes, int n_in,
                              void* d_out, int out_size, void* d_ws, size_t ws_size,
                              hipStream_t stream) {
    const float* x  = (const float*)d_in[0];
    const int*   ei = (const int*)d_in[1];
    const float* Wl = (const float*)d_in[2];
    const float* bl = (const float*)d_in[3];
    const float* Wr = (const float*)d_in[4];
    const float* W1 = (const float*)d_in[5];
    const float* b1 = (const float*)d_in[6];
    const float* W2 = (const float*)d_in[7];
    const float* b2 = (const float*)d_in[8];
    float* out = (float*)d_out;

    // ---- workspace layout (same as round 9) ----
    int* counts  = (int*)d_ws;                      // NN (reused as cursor for fill)
    int* offsets = counts + NN;                     // NN+1
    int* bsums   = offsets + NN + 1;                // 64
    int* bbase   = bsums + 64;                      // 64
    int* csr     = bbase + 64;                      // NE
    size_t fixed = ((size_t)(NN + NN + 1 + 128 + NE) * sizeof(int) + 255) & ~(size_t)255;
    ushort* xb   = (ushort*)((char*)d_ws + fixed);  // NN*DIM bf16
    ushort* bufA = xb + (size_t)NN * DIM;
    ushort* bufB = bufA + (size_t)NN * DIM;
    ushort* Wlb  = bufB + (size_t)NN * DIM;         // 12*128*128
    ushort* Wrb  = Wlb + (size_t)NL * DIM * DIM;
    ushort* W1b  = Wrb + (size_t)NL * DIM * DIM;    // 128*128

    const int* src = ei;
    const int* dst = ei + NE;

    hipMemsetAsync(counts, 0, NN * sizeof(int), stream);
    prep_kernel<<<(NCVT + 255) / 256, 256, 0, stream>>>(x, Wl, Wr, W1, xb, Wlb, Wrb, W1b,
                                                        dst, counts);
    const int NB = (NN + 1023) / 1024;   // 49
    scan1_kernel<<<NB, 1024, 0, stream>>>(counts, offsets, bsums);
    scan2_kernel<<<1, 64, 0, stream>>>(bsums, bbase, NB);
    scan3_kernel<<<(NN + 1 + 255) / 256, 256, 0, stream>>>(offsets, bbase);
    hipMemsetAsync(counts, 0, NN * sizeof(int), stream);          // reuse as cursor
    fill_kernel<<<(NE + 255) / 256, 256, 0, stream>>>(src, dst, offsets, counts, csr);

    static const int AGGRS[NL] = {0, 1, 2, 0, 1, 2, 0, 1, 2, 0, 2, 1};
    dim3 agrd((NN * 64 + 255) / 256);    // 12500 blocks: wave per node
    dim3 ggrd((NN + 127) / 128);         // 391 blocks
    // 3-buffer rotation: h -> agg -> out, all distinct (no in-place, no restrict UB)
    ushort* B[3] = {xb, bufA, bufB};
    int hi = 0;
    for (int i = 0; i < NL; ++i) {
        int ai = (hi + 1) % 3, oi = (hi + 2) % 3;
        const ushort* h = B[hi];
        if (AGGRS[i] == 0)
            aggregate_kernel<0><<<agrd, 256, 0, stream>>>(h, B[ai], csr, offsets);
        else if (AGGRS[i] == 1)
            aggregate_kernel<1><<<agrd, 256, 0, stream>>>(h, B[ai], csr, offsets);
        else
            aggregate_kernel<2><<<agrd, 256, 0, stream>>>(h, B[ai], csr, offsets);
        gemm_kernel<2><<<ggrd, 256, 0, stream>>>(B[ai], Wlb + (size_t)i * DIM * DIM, h,
                                                 Wrb + (size_t)i * DIM * DIM,
                                                 bl + (size_t)i * DIM, B[oi]);
        hi = oi;
    }
    // final MLP: relu(h@W1^T + b1) -> spare buffer, then 128->2 projection
    int fi = (hi + 1) % 3;
    gemm_kernel<1><<<ggrd, 256, 0, stream>>>(B[hi], W1b, nullptr, nullptr, b1, B[fi]);
    out_kernel<<<agrd, 256, 0, stream>>>(B[fi], W2, b2, out);
}

// Round 12
// 611.090 us; speedup vs baseline: 1.6407x; 1.0059x over previous
//
#include <hip/hip_runtime.h>
#include <math.h>

#define NN 50000
#define NE 600000
#define DIM 128
#define NL 12

typedef short bf16x8 __attribute__((ext_vector_type(8)));
typedef float f32x4 __attribute__((ext_vector_type(4)));

__device__ __forceinline__ uint f2b_rne(float f) {
    uint u = __float_as_uint(f);
    return (u + 0x7fffu + ((u >> 16) & 1u)) >> 16;
}

#define NX8 (NN * DIM / 8)               // 800000
#define NW8 (NL * DIM * DIM / 8)         // 24576
#define NW18 (DIM * DIM / 8)             // 2048
#define NCVT (NX8 + 2 * NW8 + NW18)      // 851200

// ---------------- prep: fused bf16 convert (all tensors) + degree count ----------------
__global__ void prep_kernel(const float* __restrict__ x, const float* __restrict__ Wl,
                            const float* __restrict__ Wr, const float* __restrict__ W1,
                            ushort* __restrict__ xb, ushort* __restrict__ Wlb,
                            ushort* __restrict__ Wrb, ushort* __restrict__ W1b,
                            const int* __restrict__ dst, int* __restrict__ counts) {
    int i = blockIdx.x * blockDim.x + threadIdx.x;
    if (i < NE) atomicAdd(&counts[dst[i]], 1);
    const float* in; ushort* out; int off;
    if (i < NX8)                        { in = x;  out = xb;  off = i; }
    else if (i < NX8 + NW8)             { in = Wl; out = Wlb; off = i - NX8; }
    else if (i < NX8 + 2 * NW8)         { in = Wr; out = Wrb; off = i - NX8 - NW8; }
    else if (i < NCVT)                  { in = W1; out = W1b; off = i - NX8 - 2 * NW8; }
    else return;
    const float4* p = reinterpret_cast<const float4*>(in);
    float4 v0 = p[off * 2], v1 = p[off * 2 + 1];
    uint4 o;
    o.x = (f2b_rne(v0.y) << 16) | f2b_rne(v0.x);
    o.y = (f2b_rne(v0.w) << 16) | f2b_rne(v0.z);
    o.z = (f2b_rne(v1.y) << 16) | f2b_rne(v1.x);
    o.w = (f2b_rne(v1.w) << 16) | f2b_rne(v1.z);
    reinterpret_cast<uint4*>(out)[off] = o;
}

// ---------------- CSR build ----------------
__global__ __launch_bounds__(1024) void scan1_kernel(const int* __restrict__ counts,
                                                     int* __restrict__ offsets,
                                                     int* __restrict__ bsums) {
    int b = blockIdx.x, t = threadIdx.x;
    int i = b * 1024 + t;
    int lane = t & 63, wid = t >> 6;
    int val = (i < NN) ? counts[i] : 0;
#pragma unroll
    for (int o = 1; o < 64; o <<= 1) {
        int n = __shfl_up(val, o);
        if (lane >= o) val += n;
    }
    __shared__ int ws[16];
    if (lane == 63) ws[wid] = val;
    __syncthreads();
    if (wid == 0 && lane < 16) {
        int s = ws[lane];
#pragma unroll
        for (int o = 1; o < 16; o <<= 1) {
            int n = __shfl_up(s, o);
            if (lane >= o) s += n;
        }
        ws[lane] = s;
    }
    __syncthreads();
    if (wid) val += ws[wid - 1];
    if (i < NN) offsets[i + 1] = val;
    if (t == 1023) bsums[b] = val;
}

__global__ void scan2_kernel(const int* __restrict__ bsums, int* __restrict__ bbase, int nb) {
    int lane = threadIdx.x;
    int v = (lane < nb) ? bsums[lane] : 0;
    int val = v;
#pragma unroll
    for (int o = 1; o < 64; o <<= 1) {
        int n = __shfl_up(val, o);
        if (lane >= o) val += n;
    }
    if (lane < nb) bbase[lane] = val - v;   // exclusive
}

__global__ void scan3_kernel(int* __restrict__ offsets, const int* __restrict__ bbase) {
    int i = blockIdx.x * blockDim.x + threadIdx.x;
    if (i == 0) { offsets[0] = 0; return; }
    if (i <= NN) offsets[i] += bbase[(i - 1) >> 10];
}

__global__ void fill_kernel(const int* __restrict__ src, const int* __restrict__ dst,
                            const int* __restrict__ offsets, int* __restrict__ cursor,
                            int* __restrict__ csr) {
    int e = blockIdx.x * blockDim.x + threadIdx.x;
    if (e < NE) {
        int d = dst[e];
        int p = atomicAdd(&cursor[d], 1);
        csr[offsets[d] + p] = src[e];
    }
}

// ---------------- aggregation: TWO nodes per wave, 32 gathers in flight ----------------
// Per batch: one lane-parallel csr load (lanes 0-15: node A indices, 16-31: node B),
// readlane -> wave-uniform SGPR row base per gather (cheap addressing), 32 unconditional
// row-gathers (clamped tail = cached-row dup), sched_barrier, then guarded accumulate.
// AGGR: 0=sum, 1=mean, 2=max
template <int AGGR>
__global__ __launch_bounds__(256) void aggregate_kernel(
    const ushort* __restrict__ h, ushort* __restrict__ agg,
    const int* __restrict__ csr, const int* __restrict__ offsets) {
    int wv = (blockIdx.x * blockDim.x + threadIdx.x) >> 6;   // wave id, 2 nodes each
    int l = threadIdx.x & 63;
    if (wv >= NN / 2) return;
    int na = wv * 2, nb = na + 1;            // NN even -> nb always valid
    int s0a = offsets[na], s1a = offsets[na + 1];
    int s0b = offsets[nb], s1b = offsets[nb + 1];
    const uint* hp = reinterpret_cast<const uint*>(h);   // row = 64 uints
    float axa, aya, axb, ayb;
    if (AGGR == 2) { axa = aya = axb = ayb = -INFINITY; } else { axa = aya = axb = ayb = 0.f; }
    int ea = s0a, eb = s0b;
    while (ea < s1a || eb < s1b) {
        int rema = s1a - ea, remb = s1b - eb;
        int q15 = l & 15;
        int ia = max(min(ea + q15, s1a - 1), 0);     // clamped into [0, NE-1]
        int ib = max(min(eb + q15, s1b - 1), 0);
        int mycsr = csr[((l & 31) < 16) ? ia : ib];  // lanes 0-15: A, 16-31: B (32-63 dup)
        uint u[32];
#pragma unroll
        for (int q = 0; q < 16; ++q) {
            int sa = __builtin_amdgcn_readlane(mycsr, q);
            u[q] = hp[(uint)sa * 64u + (uint)l];
        }
#pragma unroll
        for (int q = 0; q < 16; ++q) {
            int sb = __builtin_amdgcn_readlane(mycsr, 16 + q);
            u[16 + q] = hp[(uint)sb * 64u + (uint)l];
        }
        __builtin_amdgcn_sched_barrier(0);   // all 32 loads issued before any use
#pragma unroll
        for (int q = 0; q < 16; ++q) {
            if (q < rema) {
                float fx = __uint_as_float(u[q] << 16);
                float fy = __uint_as_float(u[q] & 0xffff0000u);
                if (AGGR == 2) { axa = fmaxf(axa, fx); aya = fmaxf(aya, fy); }
                else           { axa += fx;            aya += fy; }
            }
        }
#pragma unroll
        for (int q = 0; q < 16; ++q) {
            if (q < remb) {
                float fx = __uint_as_float(u[16 + q] << 16);
                float fy = __uint_as_float(u[16 + q] & 0xffff0000u);
                if (AGGR == 2) { axb = fmaxf(axb, fx); ayb = fmaxf(ayb, fy); }
                else           { axb += fx;            ayb += fy; }
            }
        }
        ea += 16; eb += 16;
    }
    int dega = s1a - s0a, degb = s1b - s0b;
    if (AGGR == 1) {
        float inva = 1.f / (float)(dega > 0 ? dega : 1);
        float invb = 1.f / (float)(degb > 0 ? degb : 1);
        axa *= inva; aya *= inva; axb *= invb; ayb *= invb;
    }
    if (AGGR == 2) {
        if (dega == 0) { axa = aya = 0.f; }
        if (degb == 0) { axb = ayb = 0.f; }
    }
    reinterpret_cast<uint*>(agg)[(uint)na * 64u + (uint)l] = (f2b_rne(aya) << 16) | f2b_rne(axa);
    reinterpret_cast<uint*>(agg)[(uint)nb * 64u + (uint)l] = (f2b_rne(ayb) << 16) | f2b_rne(axb);
}

// ---------------- MFMA GEMM, 32KB LDS-staged W (restaged per pass), swapped operands ------
// C[n][:] = relu(A1[n] @ Wa^T [+ A2[n] @ Wb^T] + bias); C distinct from A1/A2 (no aliasing).
// 32KB LDS (single W at a time) -> 4+ blocks/CU for better A-load latency hiding.
// XOR swizzle byte^=(row&7)<<4; mfma(W-frag, node-frag) -> D[outcol][node]; uint2 stores.
template <int NPASS>
__global__ __launch_bounds__(256) void gemm_kernel(
    const ushort* __restrict__ A1, const ushort* __restrict__ Wa,
    const ushort* __restrict__ A2, const ushort* __restrict__ Wb,
    const float* __restrict__ bias, ushort* __restrict__ C) {
    __shared__ ushort Wlds[DIM * DIM];     // 32KB, restaged per pass
    int t = threadIdx.x, w = t >> 6, l = t & 63;
    int lr = l & 15, lg = l >> 4;
    int row0 = blockIdx.x * 128 + w * 32;
    f32x4 acc[2][8];
#pragma unroll
    for (int rf = 0; rf < 2; ++rf)
#pragma unroll
        for (int c = 0; c < 8; ++c) acc[rf][c] = (f32x4){0.f, 0.f, 0.f, 0.f};
    int grow0 = min(row0 + lr, NN - 1);        // clamp; OOB discarded at store
    int grow1 = min(row0 + 16 + lr, NN - 1);

#pragma unroll
    for (int pass = 0; pass < NPASS; ++pass) {
        if (pass) __syncthreads();             // previous-pass LDS reads complete
        const uint4* Wv = reinterpret_cast<const uint4*>(pass ? Wb : Wa);
        char* base = reinterpret_cast<char*>(Wlds);
#pragma unroll
        for (int i = 0; i < 8; ++i) {
            int chunk = t + i * 256;           // 16B chunk id, 0..2047
            uint4 v = Wv[chunk];
            int byte = chunk << 4;
            int row = byte >> 8;
            *reinterpret_cast<uint4*>(base + (byte ^ ((row & 7) << 4))) = v;
        }
        __syncthreads();
        const ushort* A = pass ? A2 : A1;
#pragma unroll
        for (int kk = 0; kk < 4; ++kk) {
            int ko = kk * 32 + lg * 8;
            bf16x8 nf0 = *reinterpret_cast<const bf16x8*>(A + (size_t)grow0 * DIM + ko);
            bf16x8 nf1 = *reinterpret_cast<const bf16x8*>(A + (size_t)grow1 * DIM + ko);
#pragma unroll
            for (int c = 0; c < 8; ++c) {
                int wbyte = (((c * 16 + lr) << 8) + (ko << 1)) ^ ((lr & 7) << 4);
                bf16x8 wf = *reinterpret_cast<const bf16x8*>(base + wbyte);
                acc[0][c] = __builtin_amdgcn_mfma_f32_16x16x32_bf16(wf, nf0, acc[0][c], 0, 0, 0);
                acc[1][c] = __builtin_amdgcn_mfma_f32_16x16x32_bf16(wf, nf1, acc[1][c], 0, 0, 0);
            }
        }
    }
#pragma unroll
    for (int rf = 0; rf < 2; ++rf) {
        int orow = row0 + rf * 16 + lr;
        if (orow < NN) {
#pragma unroll
            for (int c = 0; c < 8; ++c) {
                int col0 = c * 16 + lg * 4;
                float4 b4 = *reinterpret_cast<const float4*>(bias + col0);
                float v0 = fmaxf(acc[rf][c][0] + b4.x, 0.f);
                float v1 = fmaxf(acc[rf][c][1] + b4.y, 0.f);
                float v2 = fmaxf(acc[rf][c][2] + b4.z, 0.f);
                float v3 = fmaxf(acc[rf][c][3] + b4.w, 0.f);
                uint2 o;
                o.x = (f2b_rne(v1) << 16) | f2b_rne(v0);
                o.y = (f2b_rne(v3) << 16) | f2b_rne(v2);
                *reinterpret_cast<uint2*>(C + (size_t)orow * DIM + col0) = o;
            }
        }
    }
}

// ---------------- final 128 -> 2 projection ----------------
__global__ void out_kernel(const ushort* __restrict__ h2, const float* __restrict__ W2,
                           const float* __restrict__ b2, float* __restrict__ out) {
    int wid = (blockIdx.x * blockDim.x + threadIdx.x) >> 6;
    int lane = threadIdx.x & 63;
    if (wid >= NN) return;
    uint u = reinterpret_cast<const uint*>(h2)[(uint)wid * 64u + (uint)lane];
    float vx = __uint_as_float(u << 16), vy = __uint_as_float(u & 0xffff0000u);
    float2 w0 = *reinterpret_cast<const float2*>(W2 + lane * 2);
    float2 w1 = *reinterpret_cast<const float2*>(W2 + DIM + lane * 2);
    float s0 = vx * w0.x + vy * w0.y;
    float s1 = vx * w1.x + vy * w1.y;
    for (int off = 32; off; off >>= 1) {
        s0 += __shfl_down(s0, off);
        s1 += __shfl_down(s1, off);
    }
    if (lane == 0) {
        out[wid * 2 + 0] = s0 + b2[0];
        out[wid * 2 + 1] = s1 + b2[1];
    }
}

extern "C" void kernel_launch(void* const* d_in, const int* in_sizes, int n_in,
                              void* d_out, int out_size, void* d_ws, size_t ws_size,
                              hipStream_t stream) {
    const float* x  = (const float*)d_in[0];
    const int*   ei = (const int*)d_in[1];
    const float* Wl = (const float*)d_in[2];
    const float* bl = (const float*)d_in[3];
    const float* Wr = (const float*)d_in[4];
    const float* W1 = (const float*)d_in[5];
    const float* b1 = (const float*)d_in[6];
    const float* W2 = (const float*)d_in[7];
    const float* b2 = (const float*)d_in[8];
    float* out = (float*)d_out;

    // ---- workspace layout ----
    int* counts  = (int*)d_ws;                      // NN (reused as cursor for fill)
    int* offsets = counts + NN;                     // NN+1
    int* bsums   = offsets + NN + 1;                // 64
    int* bbase   = bsums + 64;                      // 64
    int* csr     = bbase + 64;                      // NE
    size_t fixed = ((size_t)(NN + NN + 1 + 128 + NE) * sizeof(int) + 255) & ~(size_t)255;
    ushort* xb   = (ushort*)((char*)d_ws + fixed);  // NN*DIM bf16
    ushort* bufA = xb + (size_t)NN * DIM;
    ushort* bufB = bufA + (size_t)NN * DIM;
    ushort* Wlb  = bufB + (size_t)NN * DIM;         // 12*128*128
    ushort* Wrb  = Wlb + (size_t)NL * DIM * DIM;
    ushort* W1b  = Wrb + (size_t)NL * DIM * DIM;    // 128*128

    const int* src = ei;
    const int* dst = ei + NE;

    hipMemsetAsync(counts, 0, NN * sizeof(int), stream);
    prep_kernel<<<(NCVT + 255) / 256, 256, 0, stream>>>(x, Wl, Wr, W1, xb, Wlb, Wrb, W1b,
                                                        dst, counts);
    const int NB = (NN + 1023) / 1024;   // 49
    scan1_kernel<<<NB, 1024, 0, stream>>>(counts, offsets, bsums);
    scan2_kernel<<<1, 64, 0, stream>>>(bsums, bbase, NB);
    scan3_kernel<<<(NN + 1 + 255) / 256, 256, 0, stream>>>(offsets, bbase);
    hipMemsetAsync(counts, 0, NN * sizeof(int), stream);          // reuse as cursor
    fill_kernel<<<(NE + 255) / 256, 256, 0, stream>>>(src, dst, offsets, counts, csr);

    static const int AGGRS[NL] = {0, 1, 2, 0, 1, 2, 0, 1, 2, 0, 2, 1};
    dim3 agrd((NN / 2 * 64 + 255) / 256);   // 6250 blocks: wave per 2 nodes
    dim3 ogrd((NN * 64 + 255) / 256);       // out_kernel: wave per node
    dim3 ggrd((NN + 127) / 128);            // 391 blocks
    // 3-buffer rotation: h -> agg -> out, all distinct (no in-place, no restrict UB)
    ushort* B[3] = {xb, bufA, bufB};
    int hi = 0;
    for (int i = 0; i < NL; ++i) {
        int ai = (hi + 1) % 3, oi = (hi + 2) % 3;
        const ushort* h = B[hi];
        if (AGGRS[i] == 0)
            aggregate_kernel<0><<<agrd, 256, 0, stream>>>(h, B[ai], csr, offsets);
        else if (AGGRS[i] == 1)
            aggregate_kernel<1><<<agrd, 256, 0, stream>>>(h, B[ai], csr, offsets);
        else
            aggregate_kernel<2><<<agrd, 256, 0, stream>>>(h, B[ai], csr, offsets);
        gemm_kernel<2><<<ggrd, 256, 0, stream>>>(B[ai], Wlb + (size_t)i * DIM * DIM, h,
                                                 Wrb + (size_t)i * DIM * DIM,
                                                 bl + (size_t)i * DIM, B[oi]);
        hi = oi;
    }
    // final MLP: relu(h@W1^T + b1) -> spare buffer, then 128->2 projection
    int fi = (hi + 1) % 3;
    gemm_kernel<1><<<ggrd, 256, 0, stream>>>(B[hi], W1b, nullptr, nullptr, b1, B[fi]);
    out_kernel<<<ogrd, 256, 0, stream>>>(B[fi], W2, b2, out);
}